// Round 11
// baseline (167.584 us; speedup 1.0000x reference)
//
#include <hip/hip_runtime.h>
#include <hip/hip_fp16.h>

// GCN: h1 = relu(GCNConv(x,W1,b1)); h2 = relu(GCNConv(h1,W2,b2));
// g = max over nodes; out = log_softmax(g@fcW + fcb)
// Per node: out[v] = dinv[v]*( Σ_{u->v} dinv[u]*h[u] + dinv[v]*h[v] )@W + b
//
// Round 11: (1) revert gather32 grid to 2048 (4096 was neutral-negative —
// tail + 2x partial rows, no MLP gain). (2) Buckets 128->64 nodes (BSH 6):
// k_reorder's per-block serial depth halves, block count doubles (1563
// blocks ~ 6 waves/CU); k_bin LDS hists sized 2048 (16 KB).
// Pooling stays atomic-free (R7: 65k atomicMax on 2 lines = +160 µs).
// Assumes N <= 131072 (17-bit packing), NBK <= 2048.

#define TPB 256
#define TPB_BIN 1024
#define BSH 6                  // bucket = node >> 6  (64 nodes/bucket)
#define BN  64
#define BIN_CHUNK 6400         // edges per binning block
#define G2_BLOCKS 2048
#define RED_BLOCKS 32          // G2_BLOCKS/RED_BLOCKS rows folded per block

static __device__ __forceinline__ void acc8(float a[8], uint4 u) {
    float2 f0 = __half22float2(*(__half2*)&u.x);
    float2 f1 = __half22float2(*(__half2*)&u.y);
    float2 f2 = __half22float2(*(__half2*)&u.z);
    float2 f3 = __half22float2(*(__half2*)&u.w);
    a[0] += f0.x; a[1] += f0.y; a[2] += f1.x; a[3] += f1.y;
    a[4] += f2.x; a[5] += f2.y; a[6] += f3.x; a[7] += f3.y;
}

// ---- binning: pack edges bucket-major, cacheline-granular writes -----------

__global__ __launch_bounds__(TPB_BIN) void
k_bin(const int* __restrict__ src, const int* __restrict__ dst,
      int* __restrict__ cursor, unsigned* __restrict__ binned,
      int E, int NBK, int CAP) {
    __shared__ int hist[2048];
    __shared__ int base[2048];
    int t = threadIdx.x;
    int beg = blockIdx.x * BIN_CHUNK;
    int end = min(beg + BIN_CHUNK, E);
    for (int i = t; i < NBK; i += TPB_BIN) hist[i] = 0;
    __syncthreads();
    unsigned wc[7];
    int      bc[7];
    int ne = 0;
    for (int i = beg + t; i < end; i += TPB_BIN) {
        int d = dst[i], s = src[i];
        int b = d >> BSH;
        wc[ne] = (unsigned)s | ((unsigned)(d & (BN - 1)) << 17);
        bc[ne] = b;
        ne++;
        atomicAdd(&hist[b], 1);
    }
    __syncthreads();
    for (int b = t; b < NBK; b += TPB_BIN) {
        int c = hist[b];
        base[b] = c ? atomicAdd(&cursor[b], c) : 0;
        hist[b] = 0;
    }
    __syncthreads();
    for (int k = 0; k < ne; ++k) {
        int b = bc[k];
        int r = atomicAdd(&hist[b], 1);
        int pos = base[b] + r;
        if (pos < CAP) binned[(size_t)b * CAP + pos] = wc[k];
    }
}

// ---- per bucket: degree, dinv, rowbeg/rowend, in-place sort, xs16 ----------

__global__ void k_reorder(const int* __restrict__ cursor, unsigned* __restrict__ binned,
                          const float* __restrict__ x, float* __restrict__ dinv,
                          int* __restrict__ rowbeg, int* __restrict__ rowend,
                          uint4* __restrict__ xs16, int N, int CAP) {
    __shared__ int hist[BN];
    __shared__ int offs[BN];
    __shared__ int curs[BN];
    __shared__ float sdv[BN];
    int t = threadIdx.x, b = blockIdx.x;
    int cnt = min(cursor[b], CAP);
    int gbase = b * CAP;
    unsigned ent[8];                     // ceil(CAP/TPB) <= 6
    int ne = 0;
    if (t < BN) hist[t] = 0;
    __syncthreads();
    for (int i = t; i < cnt; i += TPB) { // read ALL entries before any write
        unsigned w = binned[gbase + i];
        ent[ne++] = w;
        atomicAdd(&hist[w >> 17], 1);
    }
    __syncthreads();
    if (t < BN) offs[t] = hist[t];
    __syncthreads();
    for (int off = 1; off < BN; off <<= 1) {   // inclusive scan
        int v = 0;
        if (t >= off && t < BN) v = offs[t - off];
        __syncthreads();
        if (t < BN) offs[t] += v;
        __syncthreads();
    }
    if (t < BN) {
        int excl = offs[t] - hist[t];
        curs[t] = excl;
        float dv = rsqrtf((float)hist[t] + 1.0f);
        sdv[t] = dv;
        int v = (b << BSH) + t;
        if (v < N) {
            dinv[v] = dv;
            rowbeg[v] = gbase + excl;
            rowend[v] = gbase + excl + hist[t];
        }
    }
    __syncthreads();
    if (t < BN) {                        // xs16[v] = half8(x[v] * dinv[v])
        int vv = (b << BSH) + t;
        if (vv < N) {
            float4 a0 = ((const float4*)x)[(size_t)vv * 2];
            float4 a1 = ((const float4*)x)[(size_t)vv * 2 + 1];
            float d = sdv[t];
            __half2 h0 = __floats2half2_rn(a0.x * d, a0.y * d);
            __half2 h1 = __floats2half2_rn(a0.z * d, a0.w * d);
            __half2 h2 = __floats2half2_rn(a1.x * d, a1.y * d);
            __half2 h3 = __floats2half2_rn(a1.z * d, a1.w * d);
            uint4 u;
            u.x = *(unsigned*)&h0; u.y = *(unsigned*)&h1;
            u.z = *(unsigned*)&h2; u.w = *(unsigned*)&h3;
            xs16[vv] = u;
        }
    }
    for (int k = 0; k < ne; ++k) {       // write back node-sorted (src only)
        unsigned w = ent[k];
        int pos = atomicAdd(&curs[w >> 17], 1);
        binned[gbase + pos] = w & 0x1FFFF;
    }
}

// ---- fused layer 1: gather (8-dim) + W1/relu/W2 + prescale -> B16 ----------
// 64 nodes/block, 4 lanes/node. Butterfly shfl gives every lane the full
// 8-dim aggregate; lane l computes output features l*8..l*8+7.

__global__ void k_l1(const uint4* __restrict__ xs16, const unsigned* __restrict__ adj,
                     const int* __restrict__ rowbeg, const int* __restrict__ rowend,
                     const float* __restrict__ dinv, const float* __restrict__ W1,
                     const float* __restrict__ b1, const float* __restrict__ W2,
                     unsigned* __restrict__ B16, int N) {
    __shared__ float sW1[8 * 32];
    __shared__ float sW2[32 * 32];
    __shared__ float sH[64 * 33];        // +1 pad: kill 16-way bank conflict
    int t = threadIdx.x;
    sW1[t] = W1[t];
#pragma unroll
    for (int i = t; i < 1024; i += TPB) sW2[i] = W2[i];
    int dl = t >> 2, l = t & 3;
    int v = blockIdx.x * 64 + dl;
    bool valid = v < N;
    float a[8] = {0, 0, 0, 0, 0, 0, 0, 0};
    if (valid) {
        int beg = rowbeg[v], end = rowend[v], len = end - beg;
        int b0 = beg + ((len * l) >> 2);
        int e0 = beg + ((len * (l + 1)) >> 2);
        int j = b0;
        for (; j + 4 <= e0; j += 4) {    // 4 independent loads in flight
            int s0 = adj[j], s1 = adj[j + 1], s2 = adj[j + 2], s3 = adj[j + 3];
            uint4 u0 = xs16[s0], u1 = xs16[s1], u2 = xs16[s2], u3 = xs16[s3];
            acc8(a, u0); acc8(a, u1); acc8(a, u2); acc8(a, u3);
        }
        for (; j < e0; ++j) acc8(a, xs16[adj[j]]);
        if (l == 0) acc8(a, xs16[v]);    // self loop
    }
#pragma unroll
    for (int k = 0; k < 8; ++k) {        // butterfly: all 4 lanes get the sum
        a[k] += __shfl_xor(a[k], 1);
        a[k] += __shfl_xor(a[k], 2);
    }
    float d = valid ? dinv[v] : 0.f;
#pragma unroll
    for (int k = 0; k < 8; ++k) a[k] *= d;
    __syncthreads();                     // sW1/sW2 ready
#pragma unroll
    for (int f8 = 0; f8 < 8; ++f8) {     // h1 features l*8+f8
        int f = l * 8 + f8;
        float s = b1[f];
#pragma unroll
        for (int k = 0; k < 8; ++k) s = fmaf(a[k], sW1[k * 32 + f], s);
        sH[dl * 33 + f] = fmaxf(s, 0.f);
    }
    __syncthreads();
    if (!valid) return;
    float s[8] = {0, 0, 0, 0, 0, 0, 0, 0};
    for (int k = 0; k < 32; ++k) {
        float hk = sH[dl * 33 + k];
#pragma unroll
        for (int j = 0; j < 8; ++j) s[j] = fmaf(hk, sW2[k * 32 + l * 8 + j], s[j]);
    }
    unsigned ow[4];
#pragma unroll
    for (int p = 0; p < 4; ++p) {
        __half2 h = __floats2half2_rn(s[p * 2] * d, s[p * 2 + 1] * d);
        ow[p] = *(unsigned*)&h;
    }
    ((uint4*)B16)[(size_t)v * 4 + l] = make_uint4(ow[0], ow[1], ow[2], ow[3]);
}

// ---- layer-2 gather + per-block partial max rows (no global atomics) -------
// 16 lanes/node: chunk q=sub&3 (16 B of the 64 B row), quarter qq=sub>>2.
// shfl_xor(4)+(8) combine; partial max init 0 == relu floor; 4-wide unroll.

__global__ void k_gather32(const uint4* __restrict__ B16, const unsigned* __restrict__ adj,
                           const int* __restrict__ rowbeg, const int* __restrict__ rowend,
                           const float* __restrict__ dinv, const float* __restrict__ b2,
                           float* __restrict__ partial, int N) {
    int tid = threadIdx.x;
    int sub = tid & 15, q = sub & 3, qq = sub >> 2;
    float bb[8];
#pragma unroll
    for (int k = 0; k < 8; ++k) bb[k] = b2[q * 8 + k];
    float m[8] = {0, 0, 0, 0, 0, 0, 0, 0};
    int gstride = (gridDim.x * blockDim.x) >> 4;
    for (int v = (blockIdx.x * blockDim.x + tid) >> 4; v < N; v += gstride) {
        int beg = rowbeg[v], end = rowend[v], len = end - beg;
        int b0 = beg + ((len * qq) >> 2);
        int e0 = beg + ((len * (qq + 1)) >> 2);
        float a[8] = {0, 0, 0, 0, 0, 0, 0, 0};
        int j = b0;
        for (; j + 4 <= e0; j += 4) {    // 4 independent row loads in flight
            int s0 = adj[j], s1 = adj[j + 1], s2 = adj[j + 2], s3 = adj[j + 3];
            uint4 u0 = B16[(size_t)s0 * 4 + q];
            uint4 u1 = B16[(size_t)s1 * 4 + q];
            uint4 u2 = B16[(size_t)s2 * 4 + q];
            uint4 u3 = B16[(size_t)s3 * 4 + q];
            acc8(a, u0); acc8(a, u1); acc8(a, u2); acc8(a, u3);
        }
        for (; j < e0; ++j) acc8(a, B16[(size_t)adj[j] * 4 + q]);
        if (qq == 0) acc8(a, B16[(size_t)v * 4 + q]);   // self loop
#pragma unroll
        for (int k = 0; k < 8; ++k) {
            a[k] += __shfl_xor(a[k], 4);
            a[k] += __shfl_xor(a[k], 8);
        }
        float d = dinv[v];
#pragma unroll
        for (int k = 0; k < 8; ++k) m[k] = fmaxf(m[k], fmaf(d, a[k], bb[k]));
    }
    __shared__ float red[TPB][8];
#pragma unroll
    for (int k = 0; k < 8; ++k) red[tid][k] = m[k];
    __syncthreads();
    for (int off = 128; off >= 16; off >>= 1) {   // stride keeps sub class
        if (tid < off) {
#pragma unroll
            for (int k = 0; k < 8; ++k)
                red[tid][k] = fmaxf(red[tid][k], red[tid + off][k]);
        }
        __syncthreads();
    }
    if (tid < 4) {                                 // fold the 4 quarters
        float r[8];
#pragma unroll
        for (int k = 0; k < 8; ++k)
            r[k] = fmaxf(fmaxf(red[tid][k], red[tid + 4][k]),
                         fmaxf(red[tid + 8][k], red[tid + 12][k]));
        float* p = partial + (size_t)blockIdx.x * 32 + tid * 8;
        ((float4*)p)[0] = make_float4(r[0], r[1], r[2], r[3]);
        ((float4*)p)[1] = make_float4(r[4], r[5], r[6], r[7]);
    }
}

// ---- stage-1 reduce: fold G2_BLOCKS rows to RED_BLOCKS rows ----------------

__global__ void k_reduce(const float* __restrict__ partial, float* __restrict__ partial2) {
    __shared__ float red[TPB];
    int t = threadIdx.x;
    int f = t & 31, r0 = t >> 5;
    const int ROWS = G2_BLOCKS / RED_BLOCKS;       // 64
    const float* base = partial + (size_t)blockIdx.x * ROWS * 32;
    float m = 0.f;
    for (int r = r0; r < ROWS; r += 8) m = fmaxf(m, base[(size_t)r * 32 + f]);
    red[t] = m;
    __syncthreads();
    for (int off = 128; off >= 32; off >>= 1) {
        if (t < off) red[t] = fmaxf(red[t], red[t + off]);
        __syncthreads();
    }
    if (t < 32) partial2[(size_t)blockIdx.x * 32 + t] = red[t];
}

// ---- head: fold RED_BLOCKS rows, fc, log_softmax ---------------------------

__global__ void k_head(const float* __restrict__ partial2,
                       const float* __restrict__ fcW, const float* __restrict__ fcb,
                       float* __restrict__ out) {
    __shared__ float red[TPB];
    int t = threadIdx.x;
    int f = t & 31, r0 = t >> 5;
    float m = 0.f;
    for (int r = r0; r < RED_BLOCKS; r += 8) m = fmaxf(m, partial2[(size_t)r * 32 + f]);
    red[t] = m;
    __syncthreads();
    for (int off = 128; off >= 32; off >>= 1) {
        if (t < off) red[t] = fmaxf(red[t], red[t + off]);
        __syncthreads();
    }
    if (t != 0) return;
    float logit[5];
    float mx = -1e30f;
#pragma unroll
    for (int c = 0; c < 5; ++c) {
        float s = fcb[c];
#pragma unroll
        for (int ff = 0; ff < 32; ++ff) s += red[ff] * fcW[ff * 5 + c];
        logit[c] = s;
        mx = fmaxf(mx, s);
    }
    float lse = 0.f;
#pragma unroll
    for (int c = 0; c < 5; ++c) lse += expf(logit[c] - mx);
    lse = logf(lse) + mx;
#pragma unroll
    for (int c = 0; c < 5; ++c) out[c] = logit[c] - lse;
}

static inline size_t align256(size_t x) { return (x + 255) & ~size_t(255); }

extern "C" void kernel_launch(void* const* d_in, const int* in_sizes, int n_in,
                              void* d_out, int out_size, void* d_ws, size_t ws_size,
                              hipStream_t stream) {
    const float* x   = (const float*)d_in[0];
    const int*   ei  = (const int*)d_in[1];
    const float* W1  = (const float*)d_in[2];
    const float* b1  = (const float*)d_in[3];
    const float* W2  = (const float*)d_in[4];
    const float* b2  = (const float*)d_in[5];
    const float* fcW = (const float*)d_in[6];
    const float* fcb = (const float*)d_in[7];
    float* out = (float*)d_out;

    const int N = in_sizes[0] / 8;
    const int E = in_sizes[1] / 2;
    const int* src = ei;
    const int* dst = ei + E;

    const int NBK = (N + BN - 1) >> BSH;                  // 1563 for N=100000
    const int avg = (E + NBK - 1) / NBK;                  // ~1024
    const int CAP = ((avg + (avg >> 2) + 64) + 15) & ~15; // mean +25% +slack

    char* ws = (char*)d_ws;
    size_t off = 0;
    int*      cursor   = (int*)(ws + off);      off += align256((size_t)NBK * 4);
    float*    dinv     = (float*)(ws + off);    off += align256((size_t)N * 4);
    int*      rowbeg   = (int*)(ws + off);      off += align256((size_t)N * 4);
    int*      rowend   = (int*)(ws + off);      off += align256((size_t)N * 4);
    uint4*    xs16     = (uint4*)(ws + off);    off += align256((size_t)N * 16);
    unsigned* B16      = (unsigned*)(ws + off); off += align256((size_t)N * 64);
    float*    partial  = (float*)(ws + off);    off += align256((size_t)G2_BLOCKS * 32 * 4);
    float*    partial2 = (float*)(ws + off);    off += align256((size_t)RED_BLOCKS * 32 * 4);
    unsigned* binned   = (unsigned*)(ws + off);

    dim3 blk(TPB);

    hipMemsetAsync(cursor, 0, (size_t)NBK * 4, stream);

    k_bin<<<dim3((E + BIN_CHUNK - 1) / BIN_CHUNK), dim3(TPB_BIN), 0, stream>>>(
        src, dst, cursor, binned, E, NBK, CAP);
    k_reorder<<<dim3(NBK), blk, 0, stream>>>(cursor, binned, x, dinv, rowbeg, rowend,
                                             xs16, N, CAP);
    k_l1<<<dim3((N + 63) / 64), blk, 0, stream>>>(xs16, binned, rowbeg, rowend,
                                                  dinv, W1, b1, W2, B16, N);
    k_gather32<<<dim3(G2_BLOCKS), blk, 0, stream>>>((const uint4*)B16, binned, rowbeg,
                                                    rowend, dinv, b2, partial, N);
    k_reduce<<<dim3(RED_BLOCKS), blk, 0, stream>>>(partial, partial2);
    k_head<<<dim3(1), blk, 0, stream>>>(partial2, fcW, fcb, out);
}

// Round 12
// 155.180 us; speedup vs baseline: 1.0799x; 1.0799x over previous
//
#include <hip/hip_runtime.h>
#include <hip/hip_fp16.h>

// GCN: h1 = relu(GCNConv(x,W1,b1)); h2 = relu(GCNConv(h1,W2,b2));
// g = max over nodes; out = log_softmax(g@fcW + fcb)
// Per node: out[v] = dinv[v]*( Σ_{u->v} dinv[u]*h[u] + dinv[v]*h[v] )@W + b
//
// Round 12: exact R9 config (best measured: 158.8 µs — BSH 7 / 128-node
// buckets, BIN_CHUNK 6400, G2_BLOCKS 2048, 2-wide gather32) + k_l1 edge loop
// 4-wide unroll (the only remaining serial load chain; independent of the
// attributed R10/R11 regressions: 4096-grid tail and BSH6 write-run
// shrinkage respectively).
// Pooling stays atomic-free (R7: 65k atomicMax on 2 lines = +160 µs).
// Assumes N <= 131072 (17-bit packing), NBK <= 1024.

#define TPB 256
#define TPB_BIN 1024
#define BSH 7                  // bucket = node >> 7  (128 nodes/bucket)
#define BN  128
#define BIN_CHUNK 6400         // edges per binning block
#define G2_BLOCKS 2048
#define RED_BLOCKS 32          // G2_BLOCKS/RED_BLOCKS rows folded per block

static __device__ __forceinline__ void acc8(float a[8], uint4 u) {
    float2 f0 = __half22float2(*(__half2*)&u.x);
    float2 f1 = __half22float2(*(__half2*)&u.y);
    float2 f2 = __half22float2(*(__half2*)&u.z);
    float2 f3 = __half22float2(*(__half2*)&u.w);
    a[0] += f0.x; a[1] += f0.y; a[2] += f1.x; a[3] += f1.y;
    a[4] += f2.x; a[5] += f2.y; a[6] += f3.x; a[7] += f3.y;
}

// ---- binning: pack edges bucket-major, cacheline-granular writes -----------

__global__ __launch_bounds__(TPB_BIN) void
k_bin(const int* __restrict__ src, const int* __restrict__ dst,
      int* __restrict__ cursor, unsigned* __restrict__ binned,
      int E, int NBK, int CAP) {
    __shared__ int hist[1024];
    __shared__ int base[1024];
    int t = threadIdx.x;
    int beg = blockIdx.x * BIN_CHUNK;
    int end = min(beg + BIN_CHUNK, E);
    for (int i = t; i < NBK; i += TPB_BIN) hist[i] = 0;
    __syncthreads();
    unsigned wc[7];
    int      bc[7];
    int ne = 0;
    for (int i = beg + t; i < end; i += TPB_BIN) {
        int d = dst[i], s = src[i];
        int b = d >> BSH;
        wc[ne] = (unsigned)s | ((unsigned)(d & (BN - 1)) << 17);
        bc[ne] = b;
        ne++;
        atomicAdd(&hist[b], 1);
    }
    __syncthreads();
    for (int b = t; b < NBK; b += TPB_BIN) {
        int c = hist[b];
        base[b] = c ? atomicAdd(&cursor[b], c) : 0;
        hist[b] = 0;
    }
    __syncthreads();
    for (int k = 0; k < ne; ++k) {
        int b = bc[k];
        int r = atomicAdd(&hist[b], 1);
        int pos = base[b] + r;
        if (pos < CAP) binned[(size_t)b * CAP + pos] = wc[k];
    }
}

// ---- per bucket: degree, dinv, rowbeg/rowend, in-place sort, xs16 ----------

__global__ void k_reorder(const int* __restrict__ cursor, unsigned* __restrict__ binned,
                          const float* __restrict__ x, float* __restrict__ dinv,
                          int* __restrict__ rowbeg, int* __restrict__ rowend,
                          uint4* __restrict__ xs16, int N, int CAP) {
    __shared__ int hist[BN];
    __shared__ int offs[BN];
    __shared__ int curs[BN];
    __shared__ float sdv[BN];
    int t = threadIdx.x, b = blockIdx.x;
    int cnt = min(cursor[b], CAP);
    int gbase = b * CAP;
    unsigned ent[16];                    // ceil(CAP/TPB) <= 11
    int ne = 0;
    if (t < BN) hist[t] = 0;
    __syncthreads();
    for (int i = t; i < cnt; i += TPB) { // read ALL entries before any write
        unsigned w = binned[gbase + i];
        ent[ne++] = w;
        atomicAdd(&hist[w >> 17], 1);
    }
    __syncthreads();
    if (t < BN) offs[t] = hist[t];
    __syncthreads();
    for (int off = 1; off < BN; off <<= 1) {   // inclusive scan
        int v = 0;
        if (t >= off && t < BN) v = offs[t - off];
        __syncthreads();
        if (t < BN) offs[t] += v;
        __syncthreads();
    }
    if (t < BN) {
        int excl = offs[t] - hist[t];
        curs[t] = excl;
        float dv = rsqrtf((float)hist[t] + 1.0f);
        sdv[t] = dv;
        int v = (b << BSH) + t;
        if (v < N) {
            dinv[v] = dv;
            rowbeg[v] = gbase + excl;
            rowend[v] = gbase + excl + hist[t];
        }
    }
    __syncthreads();
    if (t < BN) {                        // xs16[v] = half8(x[v] * dinv[v])
        int vv = (b << BSH) + t;
        if (vv < N) {
            float4 a0 = ((const float4*)x)[(size_t)vv * 2];
            float4 a1 = ((const float4*)x)[(size_t)vv * 2 + 1];
            float d = sdv[t];
            __half2 h0 = __floats2half2_rn(a0.x * d, a0.y * d);
            __half2 h1 = __floats2half2_rn(a0.z * d, a0.w * d);
            __half2 h2 = __floats2half2_rn(a1.x * d, a1.y * d);
            __half2 h3 = __floats2half2_rn(a1.z * d, a1.w * d);
            uint4 u;
            u.x = *(unsigned*)&h0; u.y = *(unsigned*)&h1;
            u.z = *(unsigned*)&h2; u.w = *(unsigned*)&h3;
            xs16[vv] = u;
        }
    }
    for (int k = 0; k < ne; ++k) {       // write back node-sorted (src only)
        unsigned w = ent[k];
        int pos = atomicAdd(&curs[w >> 17], 1);
        binned[gbase + pos] = w & 0x1FFFF;
    }
}

// ---- fused layer 1: gather (8-dim) + W1/relu/W2 + prescale -> B16 ----------
// 64 nodes/block, 4 lanes/node. Butterfly shfl gives every lane the full
// 8-dim aggregate; lane l computes output features l*8..l*8+7.

__global__ void k_l1(const uint4* __restrict__ xs16, const unsigned* __restrict__ adj,
                     const int* __restrict__ rowbeg, const int* __restrict__ rowend,
                     const float* __restrict__ dinv, const float* __restrict__ W1,
                     const float* __restrict__ b1, const float* __restrict__ W2,
                     unsigned* __restrict__ B16, int N) {
    __shared__ float sW1[8 * 32];
    __shared__ float sW2[32 * 32];
    __shared__ float sH[64 * 33];        // +1 pad: kill 16-way bank conflict
    int t = threadIdx.x;
    sW1[t] = W1[t];
#pragma unroll
    for (int i = t; i < 1024; i += TPB) sW2[i] = W2[i];
    int dl = t >> 2, l = t & 3;
    int v = blockIdx.x * 64 + dl;
    bool valid = v < N;
    float a[8] = {0, 0, 0, 0, 0, 0, 0, 0};
    if (valid) {
        int beg = rowbeg[v], end = rowend[v], len = end - beg;
        int b0 = beg + ((len * l) >> 2);
        int e0 = beg + ((len * (l + 1)) >> 2);
        int j = b0;
        for (; j + 4 <= e0; j += 4) {    // 4 independent loads in flight
            int s0 = adj[j], s1 = adj[j + 1], s2 = adj[j + 2], s3 = adj[j + 3];
            uint4 u0 = xs16[s0], u1 = xs16[s1], u2 = xs16[s2], u3 = xs16[s3];
            acc8(a, u0); acc8(a, u1); acc8(a, u2); acc8(a, u3);
        }
        for (; j < e0; ++j) acc8(a, xs16[adj[j]]);
        if (l == 0) acc8(a, xs16[v]);    // self loop
    }
#pragma unroll
    for (int k = 0; k < 8; ++k) {        // butterfly: all 4 lanes get the sum
        a[k] += __shfl_xor(a[k], 1);
        a[k] += __shfl_xor(a[k], 2);
    }
    float d = valid ? dinv[v] : 0.f;
#pragma unroll
    for (int k = 0; k < 8; ++k) a[k] *= d;
    __syncthreads();                     // sW1/sW2 ready
#pragma unroll
    for (int f8 = 0; f8 < 8; ++f8) {     // h1 features l*8+f8
        int f = l * 8 + f8;
        float s = b1[f];
#pragma unroll
        for (int k = 0; k < 8; ++k) s = fmaf(a[k], sW1[k * 32 + f], s);
        sH[dl * 33 + f] = fmaxf(s, 0.f);
    }
    __syncthreads();
    if (!valid) return;
    float s[8] = {0, 0, 0, 0, 0, 0, 0, 0};
    for (int k = 0; k < 32; ++k) {
        float hk = sH[dl * 33 + k];
#pragma unroll
        for (int j = 0; j < 8; ++j) s[j] = fmaf(hk, sW2[k * 32 + l * 8 + j], s[j]);
    }
    unsigned ow[4];
#pragma unroll
    for (int p = 0; p < 4; ++p) {
        __half2 h = __floats2half2_rn(s[p * 2] * d, s[p * 2 + 1] * d);
        ow[p] = *(unsigned*)&h;
    }
    ((uint4*)B16)[(size_t)v * 4 + l] = make_uint4(ow[0], ow[1], ow[2], ow[3]);
}

// ---- layer-2 gather + per-block partial max rows (no global atomics) -------
// 16 lanes/node: chunk q=sub&3 (16 B of the 64 B row), quarter qq=sub>>2.
// shfl_xor(4)+(8) combine; partial max init 0 == relu floor.

__global__ void k_gather32(const uint4* __restrict__ B16, const unsigned* __restrict__ adj,
                           const int* __restrict__ rowbeg, const int* __restrict__ rowend,
                           const float* __restrict__ dinv, const float* __restrict__ b2,
                           float* __restrict__ partial, int N) {
    int tid = threadIdx.x;
    int sub = tid & 15, q = sub & 3, qq = sub >> 2;
    float bb[8];
#pragma unroll
    for (int k = 0; k < 8; ++k) bb[k] = b2[q * 8 + k];
    float m[8] = {0, 0, 0, 0, 0, 0, 0, 0};
    int gstride = (gridDim.x * blockDim.x) >> 4;
    for (int v = (blockIdx.x * blockDim.x + tid) >> 4; v < N; v += gstride) {
        int beg = rowbeg[v], end = rowend[v], len = end - beg;
        int b0 = beg + ((len * qq) >> 2);
        int e0 = beg + ((len * (qq + 1)) >> 2);
        float a[8] = {0, 0, 0, 0, 0, 0, 0, 0};
        int j = b0;
        for (; j + 2 <= e0; j += 2) {
            int s0 = adj[j], s1 = adj[j + 1];
            uint4 u0 = B16[(size_t)s0 * 4 + q];
            uint4 u1 = B16[(size_t)s1 * 4 + q];
            acc8(a, u0); acc8(a, u1);
        }
        for (; j < e0; ++j) acc8(a, B16[(size_t)adj[j] * 4 + q]);
        if (qq == 0) acc8(a, B16[(size_t)v * 4 + q]);   // self loop
#pragma unroll
        for (int k = 0; k < 8; ++k) {
            a[k] += __shfl_xor(a[k], 4);
            a[k] += __shfl_xor(a[k], 8);
        }
        float d = dinv[v];
#pragma unroll
        for (int k = 0; k < 8; ++k) m[k] = fmaxf(m[k], fmaf(d, a[k], bb[k]));
    }
    __shared__ float red[TPB][8];
#pragma unroll
    for (int k = 0; k < 8; ++k) red[tid][k] = m[k];
    __syncthreads();
    for (int off = 128; off >= 16; off >>= 1) {   // stride keeps sub class
        if (tid < off) {
#pragma unroll
            for (int k = 0; k < 8; ++k)
                red[tid][k] = fmaxf(red[tid][k], red[tid + off][k]);
        }
        __syncthreads();
    }
    if (tid < 4) {                                 // fold the 4 quarters
        float r[8];
#pragma unroll
        for (int k = 0; k < 8; ++k)
            r[k] = fmaxf(fmaxf(red[tid][k], red[tid + 4][k]),
                         fmaxf(red[tid + 8][k], red[tid + 12][k]));
        float* p = partial + (size_t)blockIdx.x * 32 + tid * 8;
        ((float4*)p)[0] = make_float4(r[0], r[1], r[2], r[3]);
        ((float4*)p)[1] = make_float4(r[4], r[5], r[6], r[7]);
    }
}

// ---- stage-1 reduce: fold G2_BLOCKS rows to RED_BLOCKS rows ----------------

__global__ void k_reduce(const float* __restrict__ partial, float* __restrict__ partial2) {
    __shared__ float red[TPB];
    int t = threadIdx.x;
    int f = t & 31, r0 = t >> 5;
    const int ROWS = G2_BLOCKS / RED_BLOCKS;       // 64
    const float* base = partial + (size_t)blockIdx.x * ROWS * 32;
    float m = 0.f;
    for (int r = r0; r < ROWS; r += 8) m = fmaxf(m, base[(size_t)r * 32 + f]);
    red[t] = m;
    __syncthreads();
    for (int off = 128; off >= 32; off >>= 1) {
        if (t < off) red[t] = fmaxf(red[t], red[t + off]);
        __syncthreads();
    }
    if (t < 32) partial2[(size_t)blockIdx.x * 32 + t] = red[t];
}

// ---- head: fold RED_BLOCKS rows, fc, log_softmax ---------------------------

__global__ void k_head(const float* __restrict__ partial2,
                       const float* __restrict__ fcW, const float* __restrict__ fcb,
                       float* __restrict__ out) {
    __shared__ float red[TPB];
    int t = threadIdx.x;
    int f = t & 31, r0 = t >> 5;
    float m = 0.f;
    for (int r = r0; r < RED_BLOCKS; r += 8) m = fmaxf(m, partial2[(size_t)r * 32 + f]);
    red[t] = m;
    __syncthreads();
    for (int off = 128; off >= 32; off >>= 1) {
        if (t < off) red[t] = fmaxf(red[t], red[t + off]);
        __syncthreads();
    }
    if (t != 0) return;
    float logit[5];
    float mx = -1e30f;
#pragma unroll
    for (int c = 0; c < 5; ++c) {
        float s = fcb[c];
#pragma unroll
        for (int ff = 0; ff < 32; ++ff) s += red[ff] * fcW[ff * 5 + c];
        logit[c] = s;
        mx = fmaxf(mx, s);
    }
    float lse = 0.f;
#pragma unroll
    for (int c = 0; c < 5; ++c) lse += expf(logit[c] - mx);
    lse = logf(lse) + mx;
#pragma unroll
    for (int c = 0; c < 5; ++c) out[c] = logit[c] - lse;
}

static inline size_t align256(size_t x) { return (x + 255) & ~size_t(255); }

extern "C" void kernel_launch(void* const* d_in, const int* in_sizes, int n_in,
                              void* d_out, int out_size, void* d_ws, size_t ws_size,
                              hipStream_t stream) {
    const float* x   = (const float*)d_in[0];
    const int*   ei  = (const int*)d_in[1];
    const float* W1  = (const float*)d_in[2];
    const float* b1  = (const float*)d_in[3];
    const float* W2  = (const float*)d_in[4];
    const float* b2  = (const float*)d_in[5];
    const float* fcW = (const float*)d_in[6];
    const float* fcb = (const float*)d_in[7];
    float* out = (float*)d_out;

    const int N = in_sizes[0] / 8;
    const int E = in_sizes[1] / 2;
    const int* src = ei;
    const int* dst = ei + E;

    const int NBK = (N + BN - 1) >> BSH;                  // 782 for N=100000
    const int avg = (E + NBK - 1) / NBK;                  // ~2047
    const int CAP = ((avg + (avg >> 2) + 64) + 15) & ~15; // mean +25% +slack

    char* ws = (char*)d_ws;
    size_t off = 0;
    int*      cursor   = (int*)(ws + off);      off += align256((size_t)NBK * 4);
    float*    dinv     = (float*)(ws + off);    off += align256((size_t)N * 4);
    int*      rowbeg   = (int*)(ws + off);      off += align256((size_t)N * 4);
    int*      rowend   = (int*)(ws + off);      off += align256((size_t)N * 4);
    uint4*    xs16     = (uint4*)(ws + off);    off += align256((size_t)N * 16);
    unsigned* B16      = (unsigned*)(ws + off); off += align256((size_t)N * 64);
    float*    partial  = (float*)(ws + off);    off += align256((size_t)G2_BLOCKS * 32 * 4);
    float*    partial2 = (float*)(ws + off);    off += align256((size_t)RED_BLOCKS * 32 * 4);
    unsigned* binned   = (unsigned*)(ws + off);

    dim3 blk(TPB);

    hipMemsetAsync(cursor, 0, (size_t)NBK * 4, stream);

    k_bin<<<dim3((E + BIN_CHUNK - 1) / BIN_CHUNK), dim3(TPB_BIN), 0, stream>>>(
        src, dst, cursor, binned, E, NBK, CAP);
    k_reorder<<<dim3(NBK), blk, 0, stream>>>(cursor, binned, x, dinv, rowbeg, rowend,
                                             xs16, N, CAP);
    k_l1<<<dim3((N + 63) / 64), blk, 0, stream>>>(xs16, binned, rowbeg, rowend,
                                                  dinv, W1, b1, W2, B16, N);
    k_gather32<<<dim3(G2_BLOCKS), blk, 0, stream>>>((const uint4*)B16, binned, rowbeg,
                                                    rowend, dinv, b2, partial, N);
    k_reduce<<<dim3(RED_BLOCKS), blk, 0, stream>>>(partial, partial2);
    k_head<<<dim3(1), blk, 0, stream>>>(partial2, fcW, fcb, out);
}